// Round 1
// baseline (931.534 us; speedup 1.0000x reference)
//
#include <hip/hip_runtime.h>
#include <math.h>

#define NV   5023
#define N3   15069      // NV*3
#define NB   2048
#define KBET 150
#define KEXT 192        // 150 betas + 36 pose_feature, padded to 192

// workspace layout (float offsets)
#define WS_JD    0                      // [5][453]  (450 Jdirs slots + 3 Jt) = 2265
#define WS_AEXT  2272                   // [NB][192]
#define WS_ATR   (2272 + NB*KEXT)       // [NB][5*12]

// ---------------- zero the Jdirs accumulator region ----------------
__global__ void k_zero(float* ws) {
    int i = blockIdx.x * 256 + threadIdx.x;
    if (i < 2272) ws[i] = 0.f;
}

// ---------------- Jdirs[j][k][l] = sum_v Jreg[j,v]*shapedirs[v,k,l]; Jt = Jreg@v_template
__global__ void k_jdirs(const float* __restrict__ Jreg,   // [5][NV]
                        const float* __restrict__ sdirs,  // [NV][450]
                        const float* __restrict__ vt,     // [NV][3]
                        float* __restrict__ ws) {
    int j     = blockIdx.x >> 5;   // 0..4
    int slice = blockIdx.x & 31;   // 0..31
    int start = slice * 157;
    int end   = min(start + 157, NV);
    int t = threadIdx.x;
    int s0 = t, s1 = t + 256;      // output slots, 453 total per joint
    float acc0 = 0.f, acc1 = 0.f;
    for (int v = start; v < end; ++v) {
        float w = Jreg[j * NV + v];
        if (s0 < 450)       acc0 += w * sdirs[(size_t)v * 450 + s0];
        else if (s0 < 453)  acc0 += w * vt[v * 3 + (s0 - 450)];
        if (s1 < 450)       acc1 += w * sdirs[(size_t)v * 450 + s1];
        else if (s1 < 453)  acc1 += w * vt[v * 3 + (s1 - 450)];
    }
    float* Jd = ws + WS_JD;
    if (s0 < 453) atomicAdd(&Jd[j * 453 + s0], acc0);
    if (s1 < 453) atomicAdd(&Jd[j * 453 + s1], acc1);
}

// ---------------- per-batch: J GEMV, rodrigues, chain -> Aext, Atr ----------------
__global__ void k_batch(const float* __restrict__ shp,   // [NB][100]
                        const float* __restrict__ expn,  // [NB][50]
                        const float* __restrict__ neck,  // [NB][3]
                        const float* __restrict__ jaw,   // [NB][3]
                        const float* __restrict__ eye,   // [NB][6]
                        float* __restrict__ ws) {
    __shared__ float JdL[2265];
    {
        const float* Jd = ws + WS_JD;
        for (int i = threadIdx.x; i < 2265; i += 256) JdL[i] = Jd[i];
    }
    __syncthreads();
    int b = blockIdx.x * 256 + threadIdx.x;   // 8 blocks x 256 = 2048
    float* Aext = ws + WS_AEXT + (size_t)b * KEXT;
    float* Atr  = ws + WS_ATR  + (size_t)b * 60;

    // J[j][k] = Jt + Jdirs @ betas
    float J[15];
    for (int jk = 0; jk < 15; ++jk) J[jk] = JdL[(jk / 3) * 453 + 450 + (jk % 3)];
    for (int l = 0; l < KBET; ++l) {
        float be = (l < 100) ? shp[(size_t)b * 100 + l] : expn[(size_t)b * 50 + (l - 100)];
        Aext[l] = be;
        #pragma unroll
        for (int jj = 0; jj < 5; ++jj)
            #pragma unroll
            for (int kk = 0; kk < 3; ++kk)
                J[jj * 3 + kk] += JdL[jj * 453 + kk * 150 + l] * be;
    }

    // rodrigues for 5 joints (joint 0 pose = 0)
    float R[5][9];
    for (int jj = 0; jj < 5; ++jj) {
        float rx, ry, rz;
        if (jj == 0)      { rx = 0.f; ry = 0.f; rz = 0.f; }
        else if (jj == 1) { rx = neck[b*3]; ry = neck[b*3+1]; rz = neck[b*3+2]; }
        else if (jj == 2) { rx = jaw[b*3];  ry = jaw[b*3+1];  rz = jaw[b*3+2];  }
        else if (jj == 3) { rx = eye[b*6];  ry = eye[b*6+1];  rz = eye[b*6+2];  }
        else              { rx = eye[b*6+3]; ry = eye[b*6+4]; rz = eye[b*6+5];  }
        float ax = rx + 1e-8f, ay = ry + 1e-8f, az = rz + 1e-8f;
        float angle = sqrtf(ax*ax + ay*ay + az*az);
        float inv = 1.f / angle;
        float ux = rx * inv, uy = ry * inv, uz = rz * inv;
        float c = cosf(angle), s = sinf(angle);
        float K[9] = {0.f, -uz, uy,  uz, 0.f, -ux,  -uy, ux, 0.f};
        float KK[9];
        #pragma unroll
        for (int r = 0; r < 3; ++r)
            #pragma unroll
            for (int cc = 0; cc < 3; ++cc) {
                float a = 0.f;
                #pragma unroll
                for (int m = 0; m < 3; ++m) a += K[r*3+m] * K[m*3+cc];
                KK[r*3+cc] = a;
            }
        #pragma unroll
        for (int e = 0; e < 9; ++e) R[jj][e] = s * K[e] + (1.f - c) * KK[e];
        R[jj][0] += 1.f; R[jj][4] += 1.f; R[jj][8] += 1.f;
    }

    // pose feature -> Aext[150..185]; zero-pad 186..191
    for (int jj = 1; jj < 5; ++jj)
        #pragma unroll
        for (int e = 0; e < 9; ++e)
            Aext[KBET + (jj-1)*9 + e] = R[jj][e] - ((e == 0 || e == 4 || e == 8) ? 1.f : 0.f);
    for (int e = 186; e < 192; ++e) Aext[e] = 0.f;

    // kinematic chain (parents: -1,0,1,1,1), G rows 3x4
    float G[5][12];
    #pragma unroll
    for (int r = 0; r < 3; ++r) {
        #pragma unroll
        for (int cc = 0; cc < 3; ++cc) G[0][r*4+cc] = R[0][r*3+cc];
        G[0][r*4+3] = J[r];
    }
    const int par[5] = {-1, 0, 1, 1, 1};
    for (int jj = 1; jj < 5; ++jj) {
        int p = par[jj];
        float rel[3];
        #pragma unroll
        for (int r = 0; r < 3; ++r) rel[r] = J[jj*3+r] - J[p*3+r];
        #pragma unroll
        for (int r = 0; r < 3; ++r) {
            #pragma unroll
            for (int cc = 0; cc < 3; ++cc) {
                float a = 0.f;
                #pragma unroll
                for (int m = 0; m < 3; ++m) a += G[p][r*4+m] * R[jj][m*3+cc];
                G[jj][r*4+cc] = a;
            }
            float tt = G[p][r*4+3];
            #pragma unroll
            for (int m = 0; m < 3; ++m) tt += G[p][r*4+m] * rel[m];
            G[jj][r*4+3] = tt;
        }
    }
    // A = G with translation corrected: t - R_g @ J_j
    for (int jj = 0; jj < 5; ++jj)
        #pragma unroll
        for (int r = 0; r < 3; ++r) {
            float tc = 0.f;
            #pragma unroll
            for (int m = 0; m < 3; ++m) tc += G[jj][r*4+m] * J[jj*3+m];
            Atr[jj*12 + r*4 + 0] = G[jj][r*4+0];
            Atr[jj*12 + r*4 + 1] = G[jj][r*4+1];
            Atr[jj*12 + r*4 + 2] = G[jj][r*4+2];
            Atr[jj*12 + r*4 + 3] = G[jj][r*4+3] - tc;
        }
}

// ---------------- mega: GEMM (Aext @ Bext) + v_template + LBS, fused ----------------
#define TM  64   // batch tile
#define TNV 64   // vertex tile (192 columns)
#define KC  32

__global__ __launch_bounds__(256, 3) void k_mega(
        const float* __restrict__ sdirs,  // [N3][150]
        const float* __restrict__ pdirs,  // [36][N3]
        const float* __restrict__ vt,     // [N3]
        const float* __restrict__ lbsw,   // [NV][5]
        const float* __restrict__ ws,
        float* __restrict__ out) {
    __shared__ __align__(16) float Bl[KC][196];   // [k][col], pad 192->196
    __shared__ __align__(16) float Al[KC][68];    // [k][b],   pad 64->68
    __shared__ __align__(16) float AtrS[TM * 60];

    const float* Aext = ws + WS_AEXT;
    const float* Atr  = ws + WS_ATR;

    int v0 = blockIdx.x * TNV;     // 79 blocks
    int b0 = blockIdx.y * TM;      // 32 blocks
    int n0 = v0 * 3;

    int t  = threadIdx.x;
    int tn = t & 15, tm = t >> 4;  // 16 x 16

    float acc[4][12];
    #pragma unroll
    for (int i = 0; i < 4; ++i)
        #pragma unroll
        for (int j = 0; j < 12; ++j) acc[i][j] = 0.f;

    int kk = t & 31;
    int grp = t >> 5;              // 0..7

    for (int k0 = 0; k0 < KEXT; k0 += KC) {
        __syncthreads();
        int kg = k0 + kk;
        // stage B tile: Bl[kk][c], c in 0..191 ; two K sources
        #pragma unroll
        for (int p = 0; p < 24; ++p) {
            int c = grp + 8 * p;
            int n = n0 + c;
            float vload = 0.f;
            if (n < N3) {
                if (kg < 150)      vload = sdirs[(size_t)n * 150 + kg];
                else if (kg < 186) vload = pdirs[(size_t)(kg - 150) * N3 + n];
            }
            Bl[kk][c] = vload;
        }
        // stage A tile: Al[kk][bl]
        #pragma unroll
        for (int p = 0; p < 8; ++p) {
            int bl = grp + 8 * p;
            Al[kk][bl] = Aext[(size_t)(b0 + bl) * KEXT + kg];
        }
        __syncthreads();
        // compute
        #pragma unroll
        for (int k = 0; k < KC; ++k) {
            float4 a4 = *(const float4*)&Al[k][tm * 4];
            float4 s0 = *(const float4*)&Bl[k][tn * 12];
            float4 s1 = *(const float4*)&Bl[k][tn * 12 + 4];
            float4 s2 = *(const float4*)&Bl[k][tn * 12 + 8];
            float av[4] = {a4.x, a4.y, a4.z, a4.w};
            float sv[12] = {s0.x, s0.y, s0.z, s0.w, s1.x, s1.y, s1.z, s1.w,
                            s2.x, s2.y, s2.z, s2.w};
            #pragma unroll
            for (int i = 0; i < 4; ++i)
                #pragma unroll
                for (int j = 0; j < 12; ++j)
                    acc[i][j] += av[i] * sv[j];
        }
    }

    // stage skinning transforms for this batch tile
    __syncthreads();
    for (int i = t; i < TM * 60; i += 256) AtrS[i] = Atr[(size_t)b0 * 60 + i];
    __syncthreads();

    // + v_template
    float vt12[12];
    #pragma unroll
    for (int j = 0; j < 12; ++j) {
        int n = n0 + tn * 12 + j;
        vt12[j] = (n < N3) ? vt[n] : 0.f;
    }
    #pragma unroll
    for (int i = 0; i < 4; ++i)
        #pragma unroll
        for (int j = 0; j < 12; ++j) acc[i][j] += vt12[j];

    // lbs weights for this thread's 4 vertices
    float wv[4][5];
    #pragma unroll
    for (int vvv = 0; vvv < 4; ++vvv) {
        int v = v0 + tn * 4 + vvv;
        #pragma unroll
        for (int j = 0; j < 5; ++j) wv[vvv][j] = (v < NV) ? lbsw[(size_t)v * 5 + j] : 0.f;
    }

    bool full = (v0 + tn * 4 + 3) < NV;
    #pragma unroll
    for (int i = 0; i < 4; ++i) {
        int bl = tm * 4 + i;
        float px[4], py[4], pz[4], res[12];
        #pragma unroll
        for (int vvv = 0; vvv < 4; ++vvv) {
            px[vvv] = acc[i][vvv*3]; py[vvv] = acc[i][vvv*3+1]; pz[vvv] = acc[i][vvv*3+2];
        }
        #pragma unroll
        for (int r = 0; r < 3; ++r) {
            float4 aj0 = *(const float4*)&AtrS[bl*60 +  0 + r*4];
            float4 aj1 = *(const float4*)&AtrS[bl*60 + 12 + r*4];
            float4 aj2 = *(const float4*)&AtrS[bl*60 + 24 + r*4];
            float4 aj3 = *(const float4*)&AtrS[bl*60 + 36 + r*4];
            float4 aj4 = *(const float4*)&AtrS[bl*60 + 48 + r*4];
            #pragma unroll
            for (int vvv = 0; vvv < 4; ++vvv) {
                float w0 = wv[vvv][0], w1 = wv[vvv][1], w2 = wv[vvv][2],
                      w3 = wv[vvv][3], w4 = wv[vvv][4];
                float tx = w0*aj0.x + w1*aj1.x + w2*aj2.x + w3*aj3.x + w4*aj4.x;
                float ty = w0*aj0.y + w1*aj1.y + w2*aj2.y + w3*aj3.y + w4*aj4.y;
                float tz = w0*aj0.z + w1*aj1.z + w2*aj2.z + w3*aj3.z + w4*aj4.z;
                float tw = w0*aj0.w + w1*aj1.w + w2*aj2.w + w3*aj3.w + w4*aj4.w;
                res[vvv*3 + r] = tx*px[vvv] + ty*py[vvv] + tz*pz[vvv] + tw;
            }
        }
        size_t obase = (size_t)(b0 + bl) * N3 + n0 + tn * 12;
        if (full) {
            *(float4*)&out[obase + 0] = make_float4(res[0], res[1], res[2],  res[3]);
            *(float4*)&out[obase + 4] = make_float4(res[4], res[5], res[6],  res[7]);
            *(float4*)&out[obase + 8] = make_float4(res[8], res[9], res[10], res[11]);
        } else {
            #pragma unroll
            for (int vvv = 0; vvv < 4; ++vvv) {
                int v = v0 + tn * 4 + vvv;
                if (v < NV) {
                    out[obase + vvv*3 + 0] = res[vvv*3 + 0];
                    out[obase + vvv*3 + 1] = res[vvv*3 + 1];
                    out[obase + vvv*3 + 2] = res[vvv*3 + 2];
                }
            }
        }
    }
}

extern "C" void kernel_launch(void* const* d_in, const int* in_sizes, int n_in,
                              void* d_out, int out_size, void* d_ws, size_t ws_size,
                              hipStream_t stream) {
    const float* shp  = (const float*)d_in[0];
    const float* expn = (const float*)d_in[1];
    const float* neck = (const float*)d_in[2];
    const float* jaw  = (const float*)d_in[3];
    const float* eye  = (const float*)d_in[4];
    const float* vt   = (const float*)d_in[5];
    const float* sdir = (const float*)d_in[6];
    const float* pdir = (const float*)d_in[7];
    const float* jreg = (const float*)d_in[8];
    const float* lbsw = (const float*)d_in[9];
    float* ws  = (float*)d_ws;
    float* out = (float*)d_out;

    k_zero <<<9,   256, 0, stream>>>(ws);
    k_jdirs<<<160, 256, 0, stream>>>(jreg, sdir, vt, ws);
    k_batch<<<8,   256, 0, stream>>>(shp, expn, neck, jaw, eye, ws);
    k_mega <<<dim3(79, 32), 256, 0, stream>>>(sdir, pdir, vt, lbsw, ws, out);
}

// Round 2
// 395.388 us; speedup vs baseline: 2.3560x; 2.3560x over previous
//
#include <hip/hip_runtime.h>
#include <hip/hip_bf16.h>
#include <math.h>

#define NV   5023
#define N3   15069
#define NB   2048
#define NTIL 79            // ceil(N3/192) column tiles
#define NPAD (NTIL*192)    // 15168 padded B rows

// ---- workspace byte offsets ----
#define WS_JD_B   0          // 2272 floats (Jdirs 5*453 + pad)
#define WS_ATR_B  9216       // 2048*60*4  = 491520
#define WS_AB_B   500736     // 2048*192*2 = 786432 (bf16 A)
#define WS_BB_B   1287168    // 15168*192*2 = 5824512 (bf16 B, n-major, padded)

typedef __attribute__((ext_vector_type(8))) short short8;
typedef __attribute__((ext_vector_type(4))) float floatx4;

// ---------------- zero the Jdirs accumulator region ----------------
__global__ void k_zero(char* ws) {
    int i = blockIdx.x * 256 + threadIdx.x;
    if (i < 2272) ((float*)(ws + WS_JD_B))[i] = 0.f;
}

// ---------------- Jdirs: all 5 joints per slice, one pass over sdirs ----------------
__global__ void k_jdirs(const float* __restrict__ Jreg,   // [5][NV]
                        const float* __restrict__ sdirs,  // [NV][450]
                        const float* __restrict__ vt,     // [NV][3]
                        char* __restrict__ ws) {
    int slice = blockIdx.x;        // 0..31
    int start = slice * 157;
    int end   = min(start + 157, NV);
    int t = threadIdx.x;
    int s0 = t, s1 = t + 256;      // slots 0..452 per joint
    float a0[5] = {0,0,0,0,0}, a1[5] = {0,0,0,0,0};
    for (int v = start; v < end; ++v) {
        float w[5];
        #pragma unroll
        for (int j = 0; j < 5; ++j) w[j] = Jreg[j * NV + v];
        float x0 = (s0 < 450) ? sdirs[(size_t)v * 450 + s0]
                 : (s0 < 453 ? vt[v * 3 + (s0 - 450)] : 0.f);
        float x1 = (s1 < 450) ? sdirs[(size_t)v * 450 + s1]
                 : (s1 < 453 ? vt[v * 3 + (s1 - 450)] : 0.f);
        #pragma unroll
        for (int j = 0; j < 5; ++j) { a0[j] += w[j] * x0; a1[j] += w[j] * x1; }
    }
    float* Jd = (float*)(ws + WS_JD_B);
    #pragma unroll
    for (int j = 0; j < 5; ++j) {
        if (s0 < 453) atomicAdd(&Jd[j * 453 + s0], a0[j]);
        if (s1 < 453) atomicAdd(&Jd[j * 453 + s1], a1[j]);
    }
}

// ---------------- per-batch: J GEMV, rodrigues, chain -> Ab (bf16), Atr ----------------
__global__ void k_batch(const float* __restrict__ shp,   // [NB][100]
                        const float* __restrict__ expn,  // [NB][50]
                        const float* __restrict__ neck,
                        const float* __restrict__ jaw,
                        const float* __restrict__ eye,
                        char* __restrict__ ws) {
    __shared__ float JdL[2265];
    {
        const float* Jd = (const float*)(ws + WS_JD_B);
        for (int i = threadIdx.x; i < 2265; i += 256) JdL[i] = Jd[i];
    }
    __syncthreads();
    int b = blockIdx.x * 256 + threadIdx.x;
    __hip_bfloat16* Ab = (__hip_bfloat16*)(ws + WS_AB_B) + (size_t)b * 192;
    float* Atr = (float*)(ws + WS_ATR_B) + (size_t)b * 60;

    float J[15];
    for (int jk = 0; jk < 15; ++jk) J[jk] = JdL[(jk / 3) * 453 + 450 + (jk % 3)];
    for (int l = 0; l < 150; ++l) {
        float be = (l < 100) ? shp[(size_t)b * 100 + l] : expn[(size_t)b * 50 + (l - 100)];
        Ab[l] = __float2bfloat16(be);
        #pragma unroll
        for (int jj = 0; jj < 5; ++jj)
            #pragma unroll
            for (int kk = 0; kk < 3; ++kk)
                J[jj * 3 + kk] += JdL[jj * 453 + kk * 150 + l] * be;
    }

    float R[5][9];
    for (int jj = 0; jj < 5; ++jj) {
        float rx, ry, rz;
        if (jj == 0)      { rx = 0.f; ry = 0.f; rz = 0.f; }
        else if (jj == 1) { rx = neck[b*3]; ry = neck[b*3+1]; rz = neck[b*3+2]; }
        else if (jj == 2) { rx = jaw[b*3];  ry = jaw[b*3+1];  rz = jaw[b*3+2];  }
        else if (jj == 3) { rx = eye[b*6];  ry = eye[b*6+1];  rz = eye[b*6+2];  }
        else              { rx = eye[b*6+3]; ry = eye[b*6+4]; rz = eye[b*6+5];  }
        float ax = rx + 1e-8f, ay = ry + 1e-8f, az = rz + 1e-8f;
        float angle = sqrtf(ax*ax + ay*ay + az*az);
        float inv = 1.f / angle;
        float ux = rx * inv, uy = ry * inv, uz = rz * inv;
        float c = cosf(angle), s = sinf(angle);
        float K[9] = {0.f, -uz, uy,  uz, 0.f, -ux,  -uy, ux, 0.f};
        float KK[9];
        #pragma unroll
        for (int r = 0; r < 3; ++r)
            #pragma unroll
            for (int cc = 0; cc < 3; ++cc) {
                float a = 0.f;
                #pragma unroll
                for (int m = 0; m < 3; ++m) a += K[r*3+m] * K[m*3+cc];
                KK[r*3+cc] = a;
            }
        #pragma unroll
        for (int e = 0; e < 9; ++e) R[jj][e] = s * K[e] + (1.f - c) * KK[e];
        R[jj][0] += 1.f; R[jj][4] += 1.f; R[jj][8] += 1.f;
    }

    for (int jj = 1; jj < 5; ++jj)
        #pragma unroll
        for (int e = 0; e < 9; ++e)
            Ab[150 + (jj-1)*9 + e] =
                __float2bfloat16(R[jj][e] - ((e == 0 || e == 4 || e == 8) ? 1.f : 0.f));
    for (int e = 186; e < 192; ++e) Ab[e] = __float2bfloat16(0.f);

    float G[5][12];
    #pragma unroll
    for (int r = 0; r < 3; ++r) {
        #pragma unroll
        for (int cc = 0; cc < 3; ++cc) G[0][r*4+cc] = R[0][r*3+cc];
        G[0][r*4+3] = J[r];
    }
    const int par[5] = {-1, 0, 1, 1, 1};
    for (int jj = 1; jj < 5; ++jj) {
        int p = par[jj];
        float rel[3];
        #pragma unroll
        for (int r = 0; r < 3; ++r) rel[r] = J[jj*3+r] - J[p*3+r];
        #pragma unroll
        for (int r = 0; r < 3; ++r) {
            #pragma unroll
            for (int cc = 0; cc < 3; ++cc) {
                float a = 0.f;
                #pragma unroll
                for (int m = 0; m < 3; ++m) a += G[p][r*4+m] * R[jj][m*3+cc];
                G[jj][r*4+cc] = a;
            }
            float tt = G[p][r*4+3];
            #pragma unroll
            for (int m = 0; m < 3; ++m) tt += G[p][r*4+m] * rel[m];
            G[jj][r*4+3] = tt;
        }
    }
    for (int jj = 0; jj < 5; ++jj)
        #pragma unroll
        for (int r = 0; r < 3; ++r) {
            float tc = 0.f;
            #pragma unroll
            for (int m = 0; m < 3; ++m) tc += G[jj][r*4+m] * J[jj*3+m];
            Atr[jj*12 + r*4 + 0] = G[jj][r*4+0];
            Atr[jj*12 + r*4 + 1] = G[jj][r*4+1];
            Atr[jj*12 + r*4 + 2] = G[jj][r*4+2];
            Atr[jj*12 + r*4 + 3] = G[jj][r*4+3] - tc;
        }
}

// ---------------- build padded bf16 B [NPAD][192] (n-major) ----------------
__global__ void k_bconv(const float* __restrict__ sdirs,  // [N3][150] (V,3,150 flat)
                        const float* __restrict__ pdirs,  // [36][N3]
                        char* __restrict__ ws) {
    __hip_bfloat16* Bb = (__hip_bfloat16*)(ws + WS_BB_B);
    int idx = blockIdx.x * 256 + threadIdx.x;
    const int P1 = NPAD * 192;           // 2912256
    if (idx < P1) {
        int n = idx / 192, k = idx % 192;
        if (k < 150) {
            float v = (n < N3) ? sdirs[(size_t)n * 150 + k] : 0.f;
            Bb[idx] = __float2bfloat16(v);
        } else if (k >= 186) {
            Bb[idx] = __float2bfloat16(0.f);
        }
        // k in [150,186) handled below (coalesced over n)
    } else {
        int j = idx - P1;                // 36*NPAD
        int kk = j / NPAD, n = j % NPAD;
        float v = (n < N3) ? pdirs[(size_t)kk * N3 + n] : 0.f;
        Bb[(size_t)n * 192 + 150 + kk] = __float2bfloat16(v);
    }
}

// ---------------- mega: bf16 MFMA GEMM + fused LBS epilogue ----------------
// block: 256 thr (4 waves as 2x2), tile M=128 batch x N=192 cols, K=192 (2 chunks of 96)
#define A_LDS_OFF 0          // 128 rows * 208 B = 26624
#define B_LDS_OFF 26624      // 192 rows * 208 B = 39936 -> 66560
#define VT_OFF    0          // epilogue: 64*196*4 = 50176
#define AT_OFF    50176      // 64*60*4 = 15360 -> 65536
#define SMEM_BYTES 66560

__global__ __launch_bounds__(256, 2) void k_mega(
        const char* __restrict__ ws,
        const float* __restrict__ vt,     // [N3]
        const float* __restrict__ lbsw,   // [NV][5]
        float* __restrict__ out) {
    __shared__ __align__(16) unsigned char smem[SMEM_BYTES];
    const unsigned char* AbG = (const unsigned char*)ws + WS_AB_B;
    const unsigned char* BbG = (const unsigned char*)ws + WS_BB_B;
    const float* AtrG = (const float*)(ws + WS_ATR_B);

    const int ntile = blockIdx.x;          // 0..78
    const int b0    = blockIdx.y * 128;    // 0..15 tiles
    const int t     = threadIdx.x;
    const int lane  = t & 63;
    const int wave  = t >> 6;
    const int wm = wave >> 1, wn = wave & 1;
    const int l15 = lane & 15, quad = lane >> 4;

    floatx4 acc[4][6];
    #pragma unroll
    for (int f = 0; f < 4; ++f)
        #pragma unroll
        for (int g = 0; g < 6; ++g) {
            floatx4 z = {0.f, 0.f, 0.f, 0.f};
            acc[f][g] = z;
        }

    for (int chunk = 0; chunk < 2; ++chunk) {
        __syncthreads();
        // stage A chunk: 128 rows x 192 B (96 bf16), LDS stride 208 B
        #pragma unroll
        for (int i = 0; i < 6; ++i) {
            int flat = i * 256 + t;
            int row = flat / 12, piece = flat % 12;
            const float4* src = (const float4*)(AbG + (size_t)(b0 + row) * 384 + chunk * 192 + piece * 16);
            *(float4*)(smem + A_LDS_OFF + row * 208 + piece * 16) = *src;
        }
        // stage B chunk: 192 rows x 192 B
        #pragma unroll
        for (int i = 0; i < 9; ++i) {
            int flat = i * 256 + t;
            int row = flat / 12, piece = flat % 12;
            const float4* src = (const float4*)(BbG + (size_t)(ntile * 192 + row) * 384 + chunk * 192 + piece * 16);
            *(float4*)(smem + B_LDS_OFF + row * 208 + piece * 16) = *src;
        }
        __syncthreads();
        #pragma unroll
        for (int ks = 0; ks < 3; ++ks) {
            short8 af[4], bfr[6];
            #pragma unroll
            for (int f = 0; f < 4; ++f) {
                int row = wm * 64 + f * 16 + l15;
                af[f] = *(const short8*)(smem + A_LDS_OFF + row * 208 + ks * 64 + quad * 16);
            }
            #pragma unroll
            for (int g = 0; g < 6; ++g) {
                int row = wn * 96 + g * 16 + l15;
                bfr[g] = *(const short8*)(smem + B_LDS_OFF + row * 208 + ks * 64 + quad * 16);
            }
            #pragma unroll
            for (int f = 0; f < 4; ++f)
                #pragma unroll
                for (int g = 0; g < 6; ++g)
                    acc[f][g] = __builtin_amdgcn_mfma_f32_16x16x32_bf16(af[f], bfr[g], acc[f][g], 0, 0, 0);
        }
    }
    __syncthreads();

    float* vtile = (float*)(smem + VT_OFF);   // [64][196]
    float* atrS  = (float*)(smem + AT_OFF);   // [64][60]

    for (int half = 0; half < 2; ++half) {
        if (wm == half) {
            #pragma unroll
            for (int f = 0; f < 4; ++f)
                #pragma unroll
                for (int g = 0; g < 6; ++g)
                    #pragma unroll
                    for (int r = 0; r < 4; ++r) {
                        int row = f * 16 + quad * 4 + r;
                        int col = wn * 96 + g * 16 + l15;
                        vtile[row * 196 + col] = acc[f][g][r];
                    }
        }
        for (int i = t; i < 64 * 60; i += 256)
            atrS[i] = AtrG[(size_t)(b0 + half * 64) * 60 + i];
        __syncthreads();

        // LBS in-place: thread -> row = t>>2, 16 verts starting at (t&3)*16
        {
            int row = t >> 2;
            int vbase = (t & 3) * 16;
            float ar[60];
            #pragma unroll
            for (int i = 0; i < 60; ++i) ar[i] = atrS[row * 60 + i];
            for (int vv = 0; vv < 16; ++vv) {
                int vloc = vbase + vv;
                int vglob = ntile * 64 + vloc;
                if (vglob < NV) {
                    int c0 = vloc * 3;
                    float px = vtile[row * 196 + c0 + 0] + vt[vglob * 3 + 0];
                    float py = vtile[row * 196 + c0 + 1] + vt[vglob * 3 + 1];
                    float pz = vtile[row * 196 + c0 + 2] + vt[vglob * 3 + 2];
                    float w0 = lbsw[(size_t)vglob * 5 + 0];
                    float w1 = lbsw[(size_t)vglob * 5 + 1];
                    float w2 = lbsw[(size_t)vglob * 5 + 2];
                    float w3 = lbsw[(size_t)vglob * 5 + 3];
                    float w4 = lbsw[(size_t)vglob * 5 + 4];
                    #pragma unroll
                    for (int r = 0; r < 3; ++r) {
                        float t0 = w0*ar[ 0+r*4+0] + w1*ar[12+r*4+0] + w2*ar[24+r*4+0]
                                 + w3*ar[36+r*4+0] + w4*ar[48+r*4+0];
                        float t1 = w0*ar[ 0+r*4+1] + w1*ar[12+r*4+1] + w2*ar[24+r*4+1]
                                 + w3*ar[36+r*4+1] + w4*ar[48+r*4+1];
                        float t2 = w0*ar[ 0+r*4+2] + w1*ar[12+r*4+2] + w2*ar[24+r*4+2]
                                 + w3*ar[36+r*4+2] + w4*ar[48+r*4+2];
                        float t3 = w0*ar[ 0+r*4+3] + w1*ar[12+r*4+3] + w2*ar[24+r*4+3]
                                 + w3*ar[36+r*4+3] + w4*ar[48+r*4+3];
                        vtile[row * 196 + c0 + r] = t0*px + t1*py + t2*pz + t3;
                    }
                }
            }
        }
        __syncthreads();
        // coalesced float4 stores: consecutive lanes -> consecutive 16B
        for (int idx = t; idx < 64 * 48; idx += 256) {
            int row = idx / 48, c4 = idx % 48;
            int n = ntile * 192 + c4 * 4;
            float4 val = *(const float4*)&vtile[row * 196 + c4 * 4];
            size_t ob = (size_t)(b0 + half * 64 + row) * N3 + n;
            if (n + 4 <= N3) {
                *(float4*)&out[ob] = val;
            } else if (n < N3) {
                const float* vs = (const float*)&val;
                for (int e = 0; e < 4; ++e) if (n + e < N3) out[ob + e] = vs[e];
            }
        }
        __syncthreads();
    }
}

extern "C" void kernel_launch(void* const* d_in, const int* in_sizes, int n_in,
                              void* d_out, int out_size, void* d_ws, size_t ws_size,
                              hipStream_t stream) {
    const float* shp  = (const float*)d_in[0];
    const float* expn = (const float*)d_in[1];
    const float* neck = (const float*)d_in[2];
    const float* jaw  = (const float*)d_in[3];
    const float* eye  = (const float*)d_in[4];
    const float* vt   = (const float*)d_in[5];
    const float* sdir = (const float*)d_in[6];
    const float* pdir = (const float*)d_in[7];
    const float* jreg = (const float*)d_in[8];
    const float* lbsw = (const float*)d_in[9];
    char* ws  = (char*)d_ws;
    float* out = (float*)d_out;

    k_zero <<<9,  256, 0, stream>>>(ws);
    k_jdirs<<<32, 256, 0, stream>>>(jreg, sdir, vt, ws);
    k_batch<<<8,  256, 0, stream>>>(shp, expn, neck, jaw, eye, ws);
    k_bconv<<<13509, 256, 0, stream>>>(sdir, pdir, ws);
    k_mega <<<dim3(NTIL, 16), 256, 0, stream>>>(ws, vt, lbsw, out);
}

// Round 3
// 356.286 us; speedup vs baseline: 2.6146x; 1.1097x over previous
//
#include <hip/hip_runtime.h>
#include <hip/hip_bf16.h>
#include <math.h>

#define NV   5023
#define N3   15069
#define NB   2048
#define NTIL 79            // ceil(N3/192) column tiles
#define NPAD (NTIL*192)    // 15168 padded B rows

// ---- workspace byte offsets ----
#define WS_JD_B   0          // 2272 floats
#define WS_ATR_B  9216       // 2048*60*4  = 491520
#define WS_PF_B   500736     // 2048*36*4  = 294912 (fp32 pose_feature)
#define WS_AB_B   795648     // 2048*192*2 = 786432 (bf16 A)
#define WS_BB_B   1582080    // 15168*192*2 = 5824512 (bf16 B, n-major, padded)

typedef __attribute__((ext_vector_type(8))) short short8;
typedef __attribute__((ext_vector_type(4))) float floatx4;

// ---------------- zero the Jdirs accumulator region ----------------
__global__ void k_zero(char* ws) {
    int i = blockIdx.x * 256 + threadIdx.x;
    if (i < 2272) ((float*)(ws + WS_JD_B))[i] = 0.f;
}

// ---------------- Jdirs: 126 slices x 40 verts ----------------
__global__ void k_jdirs(const float* __restrict__ Jreg,   // [5][NV]
                        const float* __restrict__ sdirs,  // [NV][450]
                        const float* __restrict__ vt,     // [NV][3]
                        char* __restrict__ ws) {
    int slice = blockIdx.x;        // 0..125
    int start = slice * 40;
    int end   = min(start + 40, NV);
    int t = threadIdx.x;
    int s0 = t, s1 = t + 256;
    float a0[5] = {0,0,0,0,0}, a1[5] = {0,0,0,0,0};
    for (int v = start; v < end; ++v) {
        float w[5];
        #pragma unroll
        for (int j = 0; j < 5; ++j) w[j] = Jreg[j * NV + v];
        float x0 = (s0 < 450) ? sdirs[(size_t)v * 450 + s0]
                 : (s0 < 453 ? vt[v * 3 + (s0 - 450)] : 0.f);
        float x1 = (s1 < 450) ? sdirs[(size_t)v * 450 + s1]
                 : (s1 < 453 ? vt[v * 3 + (s1 - 450)] : 0.f);
        #pragma unroll
        for (int j = 0; j < 5; ++j) { a0[j] += w[j] * x0; a1[j] += w[j] * x1; }
    }
    float* Jd = (float*)(ws + WS_JD_B);
    #pragma unroll
    for (int j = 0; j < 5; ++j) {
        if (s0 < 453) atomicAdd(&Jd[j * 453 + s0], a0[j]);
        if (s1 < 453) atomicAdd(&Jd[j * 453 + s1], a1[j]);
    }
}

// ---------------- per-batch: J GEMV, rodrigues, chain -> pf (fp32), Atr ----------------
__global__ void k_batch(const float* __restrict__ shp,
                        const float* __restrict__ expn,
                        const float* __restrict__ neck,
                        const float* __restrict__ jaw,
                        const float* __restrict__ eye,
                        char* __restrict__ ws) {
    __shared__ float JdL[2265];
    {
        const float* Jd = (const float*)(ws + WS_JD_B);
        for (int i = threadIdx.x; i < 2265; i += 256) JdL[i] = Jd[i];
    }
    __syncthreads();
    int b = blockIdx.x * 256 + threadIdx.x;
    float* pf  = (float*)(ws + WS_PF_B) + (size_t)b * 36;
    float* Atr = (float*)(ws + WS_ATR_B) + (size_t)b * 60;

    float J[15];
    for (int jk = 0; jk < 15; ++jk) J[jk] = JdL[(jk / 3) * 453 + 450 + (jk % 3)];
    for (int l = 0; l < 150; ++l) {
        float be = (l < 100) ? shp[(size_t)b * 100 + l] : expn[(size_t)b * 50 + (l - 100)];
        #pragma unroll
        for (int jj = 0; jj < 5; ++jj)
            #pragma unroll
            for (int kk = 0; kk < 3; ++kk)
                J[jj * 3 + kk] += JdL[jj * 453 + kk * 150 + l] * be;
    }

    float R[5][9];
    for (int jj = 0; jj < 5; ++jj) {
        float rx, ry, rz;
        if (jj == 0)      { rx = 0.f; ry = 0.f; rz = 0.f; }
        else if (jj == 1) { rx = neck[b*3]; ry = neck[b*3+1]; rz = neck[b*3+2]; }
        else if (jj == 2) { rx = jaw[b*3];  ry = jaw[b*3+1];  rz = jaw[b*3+2];  }
        else if (jj == 3) { rx = eye[b*6];  ry = eye[b*6+1];  rz = eye[b*6+2];  }
        else              { rx = eye[b*6+3]; ry = eye[b*6+4]; rz = eye[b*6+5];  }
        float ax = rx + 1e-8f, ay = ry + 1e-8f, az = rz + 1e-8f;
        float angle = sqrtf(ax*ax + ay*ay + az*az);
        float inv = 1.f / angle;
        float ux = rx * inv, uy = ry * inv, uz = rz * inv;
        float c = cosf(angle), s = sinf(angle);
        float K[9] = {0.f, -uz, uy,  uz, 0.f, -ux,  -uy, ux, 0.f};
        float KK[9];
        #pragma unroll
        for (int r = 0; r < 3; ++r)
            #pragma unroll
            for (int cc = 0; cc < 3; ++cc) {
                float a = 0.f;
                #pragma unroll
                for (int m = 0; m < 3; ++m) a += K[r*3+m] * K[m*3+cc];
                KK[r*3+cc] = a;
            }
        #pragma unroll
        for (int e = 0; e < 9; ++e) R[jj][e] = s * K[e] + (1.f - c) * KK[e];
        R[jj][0] += 1.f; R[jj][4] += 1.f; R[jj][8] += 1.f;
    }

    for (int jj = 1; jj < 5; ++jj)
        #pragma unroll
        for (int e = 0; e < 9; ++e)
            pf[(jj-1)*9 + e] = R[jj][e] - ((e == 0 || e == 4 || e == 8) ? 1.f : 0.f);

    float G[5][12];
    #pragma unroll
    for (int r = 0; r < 3; ++r) {
        #pragma unroll
        for (int cc = 0; cc < 3; ++cc) G[0][r*4+cc] = R[0][r*3+cc];
        G[0][r*4+3] = J[r];
    }
    const int par[5] = {-1, 0, 1, 1, 1};
    for (int jj = 1; jj < 5; ++jj) {
        int p = par[jj];
        float rel[3];
        #pragma unroll
        for (int r = 0; r < 3; ++r) rel[r] = J[jj*3+r] - J[p*3+r];
        #pragma unroll
        for (int r = 0; r < 3; ++r) {
            #pragma unroll
            for (int cc = 0; cc < 3; ++cc) {
                float a = 0.f;
                #pragma unroll
                for (int m = 0; m < 3; ++m) a += G[p][r*4+m] * R[jj][m*3+cc];
                G[jj][r*4+cc] = a;
            }
            float tt = G[p][r*4+3];
            #pragma unroll
            for (int m = 0; m < 3; ++m) tt += G[p][r*4+m] * rel[m];
            G[jj][r*4+3] = tt;
        }
    }
    for (int jj = 0; jj < 5; ++jj)
        #pragma unroll
        for (int r = 0; r < 3; ++r) {
            float tc = 0.f;
            #pragma unroll
            for (int m = 0; m < 3; ++m) tc += G[jj][r*4+m] * J[jj*3+m];
            Atr[jj*12 + r*4 + 0] = G[jj][r*4+0];
            Atr[jj*12 + r*4 + 1] = G[jj][r*4+1];
            Atr[jj*12 + r*4 + 2] = G[jj][r*4+2];
            Atr[jj*12 + r*4 + 3] = G[jj][r*4+3] - tc;
        }
}

// ---------------- build bf16 A [2048][192], fully coalesced ----------------
__global__ void k_aconv(const float* __restrict__ shp,
                        const float* __restrict__ expn,
                        char* __restrict__ ws) {
    int idx = blockIdx.x * 256 + threadIdx.x;   // < 2048*192
    int b = idx / 192, k = idx % 192;
    float v;
    if (k < 100)      v = shp[(size_t)b * 100 + k];
    else if (k < 150) v = expn[(size_t)b * 50 + (k - 100)];
    else if (k < 186) v = ((const float*)(ws + WS_PF_B))[(size_t)b * 36 + (k - 150)];
    else              v = 0.f;
    ((__hip_bfloat16*)(ws + WS_AB_B))[idx] = __float2bfloat16(v);
}

// ---------------- build bf16 B [NPAD][192]: coalesced 16B writes ----------------
__global__ void k_bconv(const float* __restrict__ sdirs,  // [N3][150]
                        const float* __restrict__ pdirs,  // [36][N3]
                        char* __restrict__ ws) {
    int idx = blockIdx.x * 256 + threadIdx.x;   // < NPAD*24
    int kg = idx % 24, n = idx / 24;
    int k0 = kg * 8;
    __hip_bfloat16 val[8];
    #pragma unroll
    for (int e = 0; e < 8; ++e) {
        int k = k0 + e;
        float v = 0.f;
        if (n < N3) {
            if (k < 150)      v = sdirs[(size_t)n * 150 + k];
            else if (k < 186) v = pdirs[(size_t)(k - 150) * N3 + n];
        }
        val[e] = __float2bfloat16(v);
    }
    *(int4*)((__hip_bfloat16*)(ws + WS_BB_B) + (size_t)n * 192 + k0) = *(int4*)val;
}

// ---------------- mega: bf16 MFMA GEMM + fused LBS epilogue ----------------
// 256 thr = 4 waves split over columns (wn=wave). M=128 batch x N=192 cols, K=192 (3 chunks of 64).
#define A_OFF  0          // 128 * 136 = 17408
#define B_OFF  17408      // 192 * 136 = 26112 -> 43520
#define S_VT   65         // vtT word stride (odd -> transpose-friendly banks)
#define VT_T_OFF 0        // 192*65*4 = 49920
#define ATR_OFF  49920    // 64*60*4 = 15360 -> 65280
#define VTQ_OFF  65280    // 192*4 = 768 -> 66048
#define LBS_OFF  66048    // 320*4 = 1280 -> 67328
#define SMEM_BYTES 67328

__global__ __launch_bounds__(256, 2) void k_mega(
        const char* __restrict__ ws,
        const float* __restrict__ vt,     // [N3]
        const float* __restrict__ lbsw,   // [NV][5]
        float* __restrict__ out) {
    __shared__ __align__(16) unsigned char smem[SMEM_BYTES];
    const unsigned char* AbG = (const unsigned char*)ws + WS_AB_B;
    const unsigned char* BbG = (const unsigned char*)ws + WS_BB_B;
    const float* AtrG = (const float*)(ws + WS_ATR_B);

    const int ntile = blockIdx.x;          // 0..78
    const int b0    = blockIdx.y * 128;    // 16 tiles
    const int t     = threadIdx.x;
    const int lane  = t & 63;
    const int wn    = t >> 6;              // wave: column quarter
    const int l15 = lane & 15, quad = lane >> 4;

    floatx4 acc[8][3];
    #pragma unroll
    for (int f = 0; f < 8; ++f)
        #pragma unroll
        for (int g = 0; g < 3; ++g) {
            floatx4 z = {0.f, 0.f, 0.f, 0.f};
            acc[f][g] = z;
        }

    for (int chunk = 0; chunk < 3; ++chunk) {
        __syncthreads();
        // A: 128 rows x 128 B
        #pragma unroll
        for (int i = 0; i < 4; ++i) {
            int flat = i * 256 + t;
            int row = flat >> 3, piece = flat & 7;
            *(float4*)(smem + A_OFF + row * 136 + piece * 16) =
                *(const float4*)(AbG + (size_t)(b0 + row) * 384 + chunk * 128 + piece * 16);
        }
        // B: 192 rows x 128 B
        #pragma unroll
        for (int i = 0; i < 6; ++i) {
            int flat = i * 256 + t;
            int row = flat >> 3, piece = flat & 7;
            *(float4*)(smem + B_OFF + row * 136 + piece * 16) =
                *(const float4*)(BbG + (size_t)(ntile * 192 + row) * 384 + chunk * 128 + piece * 16);
        }
        __syncthreads();
        #pragma unroll
        for (int ks = 0; ks < 2; ++ks) {
            short8 af[8];
            #pragma unroll
            for (int f = 0; f < 8; ++f)
                af[f] = *(const short8*)(smem + A_OFF + (f * 16 + l15) * 136 + ks * 64 + quad * 16);
            #pragma unroll
            for (int g = 0; g < 3; ++g) {
                short8 bf = *(const short8*)(smem + B_OFF + (wn * 48 + g * 16 + l15) * 136 + ks * 64 + quad * 16);
                #pragma unroll
                for (int f = 0; f < 8; ++f)
                    acc[f][g] = __builtin_amdgcn_mfma_f32_16x16x32_bf16(af[f], bf, acc[f][g], 0, 0, 0);
            }
        }
    }
    __syncthreads();

    float* vtT  = (float*)(smem + VT_T_OFF);   // [192 cols][65]
    float* atrS = (float*)(smem + ATR_OFF);    // [64][60]
    float* vtQ  = (float*)(smem + VTQ_OFF);    // [192]
    float* lbsS = (float*)(smem + LBS_OFF);    // [64][5]

    // stage per-vertex constants once (region disjoint from vtT/atrS)
    if (t < 192) { int n = ntile * 192 + t; vtQ[t] = (n < N3) ? vt[n] : 0.f; }
    for (int i = t; i < 320; i += 256) {
        int v = ntile * 64 + i / 5;
        lbsS[i] = (v < NV) ? lbsw[(size_t)v * 5 + (i % 5)] : 0.f;
    }

    for (int half = 0; half < 2; ++half) {
        __syncthreads();
        // dump acc rows [half*64, half*64+64) -> vtT[col][rl]
        #pragma unroll
        for (int ff = 0; ff < 4; ++ff) {
            int f = half * 4 + ff;
            #pragma unroll
            for (int g = 0; g < 3; ++g) {
                int col = wn * 48 + g * 16 + l15;
                int rl  = ff * 16 + quad * 4;
                #pragma unroll
                for (int r = 0; r < 4; ++r)
                    vtT[col * S_VT + rl + r] = acc[f][g][r];
            }
        }
        for (int i = t; i < 3840; i += 256)
            atrS[i] = AtrG[((size_t)b0 + half * 64) * 60 + i];
        __syncthreads();

        // LBS: lane rl = t&63 (batch row), vgrp = t>>6 (16 verts)
        {
            int rl = t & 63;
            int vgrp = t >> 6;
            float ar[60];
            #pragma unroll
            for (int i = 0; i < 60; ++i) ar[i] = atrS[rl * 60 + i];
            for (int vv = 0; vv < 16; ++vv) {
                int vloc = vgrp * 16 + vv;
                int c0 = vloc * 3;
                float w0 = lbsS[vloc*5+0], w1 = lbsS[vloc*5+1], w2 = lbsS[vloc*5+2],
                      w3 = lbsS[vloc*5+3], w4 = lbsS[vloc*5+4];
                float px = vtT[(c0+0) * S_VT + rl] + vtQ[c0+0];
                float py = vtT[(c0+1) * S_VT + rl] + vtQ[c0+1];
                float pz = vtT[(c0+2) * S_VT + rl] + vtQ[c0+2];
                float y[3];
                #pragma unroll
                for (int r = 0; r < 3; ++r) {
                    float t0 = w0*ar[ 0+r*4+0] + w1*ar[12+r*4+0] + w2*ar[24+r*4+0]
                             + w3*ar[36+r*4+0] + w4*ar[48+r*4+0];
                    float t1 = w0*ar[ 0+r*4+1] + w1*ar[12+r*4+1] + w2*ar[24+r*4+1]
                             + w3*ar[36+r*4+1] + w4*ar[48+r*4+1];
                    float t2 = w0*ar[ 0+r*4+2] + w1*ar[12+r*4+2] + w2*ar[24+r*4+2]
                             + w3*ar[36+r*4+2] + w4*ar[48+r*4+2];
                    float t3 = w0*ar[ 0+r*4+3] + w1*ar[12+r*4+3] + w2*ar[24+r*4+3]
                             + w3*ar[36+r*4+3] + w4*ar[48+r*4+3];
                    y[r] = t0*px + t1*py + t2*pz + t3;
                }
                vtT[(c0+0) * S_VT + rl] = y[0];
                vtT[(c0+1) * S_VT + rl] = y[1];
                vtT[(c0+2) * S_VT + rl] = y[2];
            }
        }
        __syncthreads();
        // transpose out: per row, 3 coalesced dword stores of 64 cols each
        {
            int wv = t >> 6;
            for (int rr = wv; rr < 64; rr += 4) {
                size_t ob = (size_t)(b0 + half * 64 + rr) * N3 + (size_t)ntile * 192;
                #pragma unroll
                for (int e = 0; e < 3; ++e) {
                    int col = e * 64 + lane;
                    float val = vtT[col * S_VT + rr];
                    if (ntile * 192 + col < N3) out[ob + col] = val;
                }
            }
        }
    }
}

extern "C" void kernel_launch(void* const* d_in, const int* in_sizes, int n_in,
                              void* d_out, int out_size, void* d_ws, size_t ws_size,
                              hipStream_t stream) {
    const float* shp  = (const float*)d_in[0];
    const float* expn = (const float*)d_in[1];
    const float* neck = (const float*)d_in[2];
    const float* jaw  = (const float*)d_in[3];
    const float* eye  = (const float*)d_in[4];
    const float* vt   = (const float*)d_in[5];
    const float* sdir = (const float*)d_in[6];
    const float* pdir = (const float*)d_in[7];
    const float* jreg = (const float*)d_in[8];
    const float* lbsw = (const float*)d_in[9];
    char* ws  = (char*)d_ws;
    float* out = (float*)d_out;

    k_zero <<<9,   256, 0, stream>>>(ws);
    k_jdirs<<<126, 256, 0, stream>>>(jreg, sdir, vt, ws);
    k_batch<<<8,   256, 0, stream>>>(shp, expn, neck, jaw, eye, ws);
    k_aconv<<<1536, 256, 0, stream>>>(shp, expn, ws);
    k_bconv<<<1422, 256, 0, stream>>>(sdir, pdir, ws);
    k_mega <<<dim3(NTIL, 16), 256, 0, stream>>>(ws, vt, lbsw, out);
}